// Round 1
// baseline (3431.511 us; speedup 1.0000x reference)
//
#include <hip/hip_runtime.h>
#include <cstdint>
#include <cstddef>

#define TT 8

#define H1_ELEMS (128*32*20*20)   // 1,638,400
#define N2_ELEMS (1024*64*81)     // 5,308,416
#define N3_ELEMS (1024*64*49)     // 3,211,264
#define E2_ELEMS (128*64*81)      // 663,552
#define E3_ELEMS (128*64*49)      // 401,408

// ---------------- conv1: [128,4,84,84] -> [128,32,20,20], k8 s4 ----------------
__global__ void k_conv1(const float* __restrict__ x, const float* __restrict__ w,
                        const float* __restrict__ bias, float* __restrict__ out) {
  int idx = blockIdx.x * 256 + threadIdx.x;
  if (idx >= H1_ELEMS) return;
  int p  = idx % 400;
  int oc = (idx / 400) & 31;
  int b  = idx / (400 * 32);
  int oy = p / 20, ox = p - oy * 20;
  const float* xb = x + (size_t)b * 4 * 7056 + (oy * 4) * 84 + ox * 4;
  const float* wk = w + oc * 256;
  float acc = 0.f;
  for (int ci = 0; ci < 4; ci++) {
    const float* xc = xb + ci * 7056;
    const float* wc = wk + ci * 64;
    #pragma unroll
    for (int ky = 0; ky < 8; ky++)
      #pragma unroll
      for (int kx = 0; kx < 8; kx++)
        acc += xc[ky * 84 + kx] * wc[ky * 8 + kx];
  }
  out[idx] = acc + bias[oc];
}

// ---------------- per-channel mean / rstd (training BN, biased var) ----------------
__global__ void k_bnstats(const float* __restrict__ xp, int NBn, int C, int HW,
                          float* __restrict__ meanArr, float* __restrict__ rstdArr) {
  int c = blockIdx.x, tid = threadIdx.x;
  long n = (long)NBn * HW;
  float s = 0.f, s2 = 0.f;
  for (long i = tid; i < n; i += 256) {
    int nb = (int)(i / HW);
    int p  = (int)(i - (long)nb * HW);
    float v = xp[((size_t)nb * C + c) * HW + p];
    s += v; s2 += v * v;
  }
  __shared__ float l0[256], l1[256];
  l0[tid] = s; l1[tid] = s2; __syncthreads();
  for (int k = 128; k > 0; k >>= 1) {
    if (tid < k) { l0[tid] += l0[tid + k]; l1[tid] += l1[tid + k]; }
    __syncthreads();
  }
  if (tid == 0) {
    float m   = l0[0] / (float)n;
    float var = l1[0] / (float)n - m * m;
    meanArr[c] = m;
    rstdArr[c] = rsqrtf(var + 1e-5f);
  }
}

// ---------------- BN + LIF for stage 1 (input identical across T) ----------------
__global__ void k_lif1(const float* __restrict__ h, const float* __restrict__ mean,
                       const float* __restrict__ rstd, const float* __restrict__ g,
                       const float* __restrict__ bb, unsigned char* __restrict__ sout) {
  int idx = blockIdx.x * 256 + threadIdx.x;
  if (idx >= H1_ELEMS) return;
  int c = (idx / 400) & 31;
  float xv = g[c] * (h[idx] - mean[c]) * rstd[c] + bb[c];
  float v = 0.f;
  #pragma unroll
  for (int t = 0; t < TT; t++) {
    v = v + (xv - v) * 0.5f;               // charge, tau=2 (exact halving)
    unsigned char s = (v >= 1.0f);
    sout[(size_t)t * H1_ELEMS + idx] = s;
    if (s) v = 0.f;                        // hard reset
  }
}

// ---------------- BN + LIF generic (x differs per t). layout [(t*128+b)*C+c]*HW+p ----
__global__ void k_lif_seq(const float* __restrict__ h, const float* __restrict__ mean,
                          const float* __restrict__ rstd, const float* __restrict__ g,
                          const float* __restrict__ bb, unsigned char* __restrict__ sout,
                          int C, int HW, int E) {
  int idx = blockIdx.x * 256 + threadIdx.x;
  if (idx >= E) return;
  int c = (idx / HW) % C;
  float gm = g[c], mm = mean[c], rs = rstd[c], bc = bb[c];
  float v = 0.f;
  #pragma unroll
  for (int t = 0; t < TT; t++) {
    float xv = h[(size_t)t * E + idx];
    xv = gm * (xv - mm) * rs + bc;
    v = v + (xv - v) * 0.5f;
    unsigned char s = (v >= 1.0f);
    sout[(size_t)t * E + idx] = s;
    if (s) v = 0.f;
  }
}

// ---------------- conv2: [1024,32,20,20](u8 spikes) -> [1024,64,9,9], k4 s2 --------
__global__ void k_conv2(const unsigned char* __restrict__ s1, const float* __restrict__ w,
                        const float* __restrict__ bias, float* __restrict__ out) {
  int idx = blockIdx.x * 256 + threadIdx.x;
  if (idx >= N2_ELEMS) return;
  int p  = idx % 81;
  int oc = (idx / 81) & 63;
  int n  = idx / (81 * 64);
  int oy = p / 9, ox = p - oy * 9;
  const unsigned char* xb = s1 + (size_t)n * 32 * 400 + (oy * 2) * 20 + ox * 2;
  const float* wk = w + oc * 512;
  float acc = 0.f;
  for (int ci = 0; ci < 32; ci++) {
    const unsigned char* xc = xb + ci * 400;
    const float* wc = wk + ci * 16;
    #pragma unroll
    for (int ky = 0; ky < 4; ky++)
      #pragma unroll
      for (int kx = 0; kx < 4; kx++)
        if (xc[ky * 20 + kx]) acc += wc[ky * 4 + kx];   // spike in {0,1}: exact
  }
  out[idx] = acc + bias[oc];
}

// ---------------- conv3: [1024,64,9,9](u8) -> [1024,64,7,7], k3 s1 ----------------
__global__ void k_conv3(const unsigned char* __restrict__ s2, const float* __restrict__ w,
                        const float* __restrict__ bias, float* __restrict__ out) {
  int idx = blockIdx.x * 256 + threadIdx.x;
  if (idx >= N3_ELEMS) return;
  int p  = idx % 49;
  int oc = (idx / 49) & 63;
  int n  = idx / (49 * 64);
  int oy = p / 7, ox = p - oy * 7;
  const unsigned char* xb = s2 + (size_t)n * 64 * 81 + oy * 9 + ox;
  const float* wk = w + oc * 576;
  float acc = 0.f;
  for (int ci = 0; ci < 64; ci++) {
    const unsigned char* xc = xb + ci * 81;
    const float* wc = wk + ci * 9;
    #pragma unroll
    for (int ky = 0; ky < 3; ky++)
      #pragma unroll
      for (int kx = 0; kx < 3; kx++)
        if (xc[ky * 9 + kx]) acc += wc[ky * 3 + kx];
  }
  out[idx] = acc + bias[oc];
}

// ---------------- fc1: [1024,3136](u8) x [512,3136] -> [1024,512] ----------------
__global__ void k_fc1(const unsigned char* __restrict__ s3, const float* __restrict__ w,
                      const float* __restrict__ bias, float* __restrict__ out) {
  __shared__ uint32_t xs[8 * 784];           // 8 rows x 3136 u8 spikes
  int tid = threadIdx.x;
  int n0 = blockIdx.x * 8;
  const uint32_t* src = (const uint32_t*)(s3 + (size_t)n0 * 3136);
  for (int i = tid; i < 6272; i += 256) xs[i] = src[i];
  __syncthreads();
  int o = blockIdx.y * 256 + tid;
  float acc[8];
  #pragma unroll
  for (int r = 0; r < 8; r++) acc[r] = 0.f;
  const float4* wr = (const float4*)(w + (size_t)o * 3136);
  for (int k4 = 0; k4 < 784; k4++) {
    float4 wv = wr[k4];
    #pragma unroll
    for (int r = 0; r < 8; r++) {
      uint32_t m = xs[r * 784 + k4];         // broadcast (same addr all lanes)
      if (m & 0x000000ffu) acc[r] += wv.x;
      if (m & 0x0000ff00u) acc[r] += wv.y;
      if (m & 0x00ff0000u) acc[r] += wv.z;
      if (m & 0xff000000u) acc[r] += wv.w;
    }
  }
  float bv = bias[o];
  #pragma unroll
  for (int r = 0; r < 8; r++) out[(size_t)(n0 + r) * 512 + o] = acc[r] + bv;
}

// ---------------- LIF over fc1 output: [8,128,512] -> spikes u8 ----------------
__global__ void k_lif_fc(const float* __restrict__ f1, unsigned char* __restrict__ hid) {
  int idx = blockIdx.x * 256 + threadIdx.x;   // < 65536
  float v = 0.f;
  #pragma unroll
  for (int t = 0; t < TT; t++) {
    float xv = f1[t * 65536 + idx];
    v = v + (xv - v) * 0.5f;
    unsigned char s = (v >= 1.0f);
    hid[t * 65536 + idx] = s;
    if (s) v = 0.f;
  }
}

// ---------------- fco + mean over T: [8,128,512](u8) -> [128,2] ----------------
__global__ void k_fco(const unsigned char* __restrict__ hid, const float* __restrict__ w,
                      const float* __restrict__ bias, float* __restrict__ out) {
  int b = blockIdx.x, tid = threadIdx.x;
  float a0 = 0.f, a1 = 0.f;
  for (int t = 0; t < TT; t++) {
    const unsigned char* hrow = hid + ((size_t)t * 128 + b) * 512;
    for (int o = tid; o < 512; o += 256) {
      if (hrow[o]) { a0 += w[o]; a1 += w[512 + o]; }
    }
  }
  __shared__ float l0[256], l1[256];
  l0[tid] = a0; l1[tid] = a1; __syncthreads();
  for (int k = 128; k > 0; k >>= 1) {
    if (tid < k) { l0[tid] += l0[tid + k]; l1[tid] += l1[tid + k]; }
    __syncthreads();
  }
  if (tid == 0) {
    out[b * 2 + 0] = l0[0] * 0.125f + bias[0];
    out[b * 2 + 1] = l1[0] * 0.125f + bias[1];
  }
}

extern "C" void kernel_launch(void* const* d_in, const int* in_sizes, int n_in,
                              void* d_out, int out_size, void* d_ws, size_t ws_size,
                              hipStream_t stream) {
  const float* x    = (const float*)d_in[0];
  const float* c1w  = (const float*)d_in[1];
  const float* c1b  = (const float*)d_in[2];
  const float* bn1g = (const float*)d_in[3];
  const float* bn1b = (const float*)d_in[4];
  const float* c2w  = (const float*)d_in[5];
  const float* c2b  = (const float*)d_in[6];
  const float* bn2g = (const float*)d_in[7];
  const float* bn2b = (const float*)d_in[8];
  const float* c3w  = (const float*)d_in[9];
  const float* c3b  = (const float*)d_in[10];
  const float* bn3g = (const float*)d_in[11];
  const float* bn3b = (const float*)d_in[12];
  const float* fc1w = (const float*)d_in[13];
  const float* fc1b = (const float*)d_in[14];
  const float* fcow = (const float*)d_in[15];
  const float* fcob = (const float*)d_in[16];
  float* out = (float*)d_out;

  char* ws = (char*)d_ws;
  // workspace layout (bytes)
  float*         h1  = (float*)(ws + 0);                 //  6,553,600
  unsigned char* s1  = (unsigned char*)(ws + 6553600);   // 13,107,200
  float*         h2  = (float*)(ws + 19660800);          // 21,233,664
  unsigned char* s2  = (unsigned char*)(ws + 40894464);  //  5,308,416
  float*         h3  = (float*)(ws + 46202880);          // 12,845,056
  unsigned char* s3  = (unsigned char*)(ws + 59047936);  //  3,211,264
  float*         f1  = (float*)(ws + 62259200);          //  2,097,152
  unsigned char* hid = (unsigned char*)(ws + 64356352);  //    524,288
  float*         st  = (float*)(ws + 64880640);          //  1,280 (stats)
  // st: mean1[32] rstd1[32] mean2[64] rstd2[64] mean3[64] rstd3[64]

  k_conv1 <<<6400, 256, 0, stream>>>(x, c1w, c1b, h1);
  k_bnstats<<<32, 256, 0, stream>>>(h1, 128, 32, 400, st, st + 32);
  k_lif1  <<<6400, 256, 0, stream>>>(h1, st, st + 32, bn1g, bn1b, s1);

  k_conv2 <<<20736, 256, 0, stream>>>(s1, c2w, c2b, h2);
  k_bnstats<<<64, 256, 0, stream>>>(h2, 1024, 64, 81, st + 64, st + 128);
  k_lif_seq<<<2592, 256, 0, stream>>>(h2, st + 64, st + 128, bn2g, bn2b, s2, 64, 81, E2_ELEMS);

  k_conv3 <<<12544, 256, 0, stream>>>(s2, c3w, c3b, h3);
  k_bnstats<<<64, 256, 0, stream>>>(h3, 1024, 64, 49, st + 192, st + 256);
  k_lif_seq<<<1568, 256, 0, stream>>>(h3, st + 192, st + 256, bn3g, bn3b, s3, 64, 49, E3_ELEMS);

  k_fc1   <<<dim3(128, 2), 256, 0, stream>>>(s3, fc1w, fc1b, f1);
  k_lif_fc<<<256, 256, 0, stream>>>(f1, hid);
  k_fco   <<<128, 256, 0, stream>>>(hid, fcow, fcob, out);
}

// Round 2
// 818.611 us; speedup vs baseline: 4.1919x; 4.1919x over previous
//
#include <hip/hip_runtime.h>
#include <cstdint>
#include <cstddef>

#define TT 8

#define H1_ELEMS (128*32*20*20)   // 1,638,400
#define N2_ELEMS (1024*64*81)     // 5,308,416
#define N3_ELEMS (1024*64*49)     // 3,211,264
#define E2_ELEMS (128*64*81)      // 663,552
#define E3_ELEMS (128*64*49)      // 401,408

// ---------------- weight transpose preps ----------------
__global__ void prep_wT2(const float* __restrict__ w, float* __restrict__ wT) {
  int i = blockIdx.x * 256 + threadIdx.x;           // 32768 = 64 oc x 512 pos
  if (i >= 64 * 512) return;
  int oc = i & 63, pos = i >> 6;
  wT[pos * 64 + oc] = w[oc * 512 + pos];
}
__global__ void prep_wT3(const float* __restrict__ w, float* __restrict__ wT) {
  int i = blockIdx.x * 256 + threadIdx.x;           // 36864 = 64 oc x 576 pos
  if (i >= 64 * 576) return;
  int oc = i & 63, pos = i >> 6;
  wT[pos * 64 + oc] = w[oc * 576 + pos];
}
__global__ void prep_wTf(const float* __restrict__ w, float* __restrict__ wT) {
  int i = blockIdx.x * 256 + threadIdx.x;           // 3136*512
  if (i >= 3136 * 512) return;
  int o = i & 511, k = i >> 9;
  wT[k * 512 + o] = w[o * 3136 + k];                // coalesced write
}

// ---------------- conv1: [128,4,84,84] -> [128,32,20,20], k8 s4 ----------------
__global__ void k_conv1(const float* __restrict__ x, const float* __restrict__ w,
                        const float* __restrict__ bias, float* __restrict__ out) {
  int idx = blockIdx.x * 256 + threadIdx.x;
  if (idx >= H1_ELEMS) return;
  int p  = idx % 400;
  int oc = (idx / 400) & 31;
  int b  = idx / (400 * 32);
  int oy = p / 20, ox = p - oy * 20;
  const float* xb = x + (size_t)b * 28224 + oy * 336 + ox * 4;  // (oy*4)*84 + ox*4
  const float* wk = w + oc * 256;
  float acc = 0.f;
  for (int ci = 0; ci < 4; ci++) {
    const float* xc = xb + ci * 7056;
    const float* wc = wk + ci * 64;
    #pragma unroll
    for (int ky = 0; ky < 8; ky++) {
      float4 xa = ((const float4*)(xc + ky * 84))[0];
      float4 xd = ((const float4*)(xc + ky * 84))[1];
      float4 wa = ((const float4*)(wc + ky * 8))[0];
      float4 wd = ((const float4*)(wc + ky * 8))[1];
      acc = fmaf(xa.x, wa.x, acc); acc = fmaf(xa.y, wa.y, acc);
      acc = fmaf(xa.z, wa.z, acc); acc = fmaf(xa.w, wa.w, acc);
      acc = fmaf(xd.x, wd.x, acc); acc = fmaf(xd.y, wd.y, acc);
      acc = fmaf(xd.z, wd.z, acc); acc = fmaf(xd.w, wd.w, acc);
    }
  }
  out[idx] = acc + bias[oc];
}

// ---------------- per-channel mean / rstd (training BN, biased var) ----------------
template <int HW>
__global__ void k_bnstats(const float* __restrict__ xp, int NBn, int C,
                          float* __restrict__ meanArr, float* __restrict__ rstdArr) {
  int c = blockIdx.x, tid = threadIdx.x;
  long n = (long)NBn * HW;
  float s = 0.f, s2 = 0.f;
  for (long i = tid; i < n; i += 256) {
    int nb = (int)(i / HW);
    int p  = (int)(i - (long)nb * HW);
    float v = xp[((size_t)nb * C + c) * HW + p];
    s += v; s2 += v * v;
  }
  __shared__ float l0[256], l1[256];
  l0[tid] = s; l1[tid] = s2; __syncthreads();
  for (int k = 128; k > 0; k >>= 1) {
    if (tid < k) { l0[tid] += l0[tid + k]; l1[tid] += l1[tid + k]; }
    __syncthreads();
  }
  if (tid == 0) {
    float m   = l0[0] / (float)n;
    float var = l1[0] / (float)n - m * m;
    meanArr[c] = m;
    rstdArr[c] = rsqrtf(var + 1e-5f);
  }
}

// ---------------- BN + LIF for stage 1 (input identical across T) ----------------
__global__ void k_lif1(const float* __restrict__ h, const float* __restrict__ mean,
                       const float* __restrict__ rstd, const float* __restrict__ g,
                       const float* __restrict__ bb, unsigned char* __restrict__ sout) {
  int idx = blockIdx.x * 256 + threadIdx.x;
  if (idx >= H1_ELEMS) return;
  int c = (idx / 400) & 31;
  float xv = g[c] * (h[idx] - mean[c]) * rstd[c] + bb[c];
  float v = 0.f;
  #pragma unroll
  for (int t = 0; t < TT; t++) {
    v = v + (xv - v) * 0.5f;
    unsigned char s = (v >= 1.0f);
    sout[(size_t)t * H1_ELEMS + idx] = s;
    if (s) v = 0.f;
  }
}

// ---------------- BN + LIF generic (x differs per t) ----------------
__global__ void k_lif_seq(const float* __restrict__ h, const float* __restrict__ mean,
                          const float* __restrict__ rstd, const float* __restrict__ g,
                          const float* __restrict__ bb, unsigned char* __restrict__ sout,
                          int C, int HW, int E) {
  int idx = blockIdx.x * 256 + threadIdx.x;
  if (idx >= E) return;
  int c = (idx / HW) % C;
  float gm = g[c], mm = mean[c], rs = rstd[c], bc = bb[c];
  float v = 0.f;
  #pragma unroll
  for (int t = 0; t < TT; t++) {
    float xv = h[(size_t)t * E + idx];
    xv = gm * (xv - mm) * rs + bc;
    v = v + (xv - v) * 0.5f;
    unsigned char s = (v >= 1.0f);
    sout[(size_t)t * E + idx] = s;
    if (s) v = 0.f;
  }
}

// ---------------- conv2: [1024,32,20,20](u8) -> [1024,64,9,9], k4 s2 ----------------
// block = 2 images, 384 thr: waves 0-2 -> oc 0..31, waves 3-5 -> oc 32..63
__global__ __launch_bounds__(384) void k_conv2(const unsigned char* __restrict__ s1,
                                               const float* __restrict__ wT,
                                               const float* __restrict__ bias,
                                               float* __restrict__ out) {
  __shared__ unsigned char sp[25600];
  int tid = threadIdx.x;
  int img0 = blockIdx.x * 2;
  {
    const uint32_t* src = (const uint32_t*)(s1 + (size_t)img0 * 12800);
    uint32_t* dst = (uint32_t*)sp;
    for (int i = tid; i < 6400; i += 384) dst[i] = src[i];
  }
  __syncthreads();
  int oh = __builtin_amdgcn_readfirstlane(tid / 192);   // wave-uniform oc-half
  int t2 = tid % 192;
  if (t2 >= 162) return;
  int li = t2 / 81;
  int p  = t2 % 81;
  int oy = p / 9, ox = p - oy * 9;
  int sbase = li * 12800 + oy * 40 + ox * 2;
  float4 acc[8] = {};
  const float* wb = wT + oh * 32;
  for (int ci = 0; ci < 32; ci++) {
    int soff = sbase + ci * 400;
    const float* w0 = wb + ci * 1024;                   // (ci*16)*64
    #pragma unroll
    for (int ky = 0; ky < 4; ky++) {
      float s0 = (float)sp[soff + ky * 20 + 0];
      float s1v = (float)sp[soff + ky * 20 + 1];
      float s2v = (float)sp[soff + ky * 20 + 2];
      float s3v = (float)sp[soff + ky * 20 + 3];
      const float* wr = w0 + ky * 256;                  // (ky*4)*64
      #pragma unroll
      for (int j = 0; j < 8; j++) {
        float4 wa = ((const float4*)(wr      ))[j];
        float4 wbv = ((const float4*)(wr +  64))[j];
        float4 wc = ((const float4*)(wr + 128))[j];
        float4 wd = ((const float4*)(wr + 192))[j];
        acc[j].x = fmaf(s0, wa.x, acc[j].x);  acc[j].y = fmaf(s0, wa.y, acc[j].y);
        acc[j].z = fmaf(s0, wa.z, acc[j].z);  acc[j].w = fmaf(s0, wa.w, acc[j].w);
        acc[j].x = fmaf(s1v, wbv.x, acc[j].x); acc[j].y = fmaf(s1v, wbv.y, acc[j].y);
        acc[j].z = fmaf(s1v, wbv.z, acc[j].z); acc[j].w = fmaf(s1v, wbv.w, acc[j].w);
        acc[j].x = fmaf(s2v, wc.x, acc[j].x); acc[j].y = fmaf(s2v, wc.y, acc[j].y);
        acc[j].z = fmaf(s2v, wc.z, acc[j].z); acc[j].w = fmaf(s2v, wc.w, acc[j].w);
        acc[j].x = fmaf(s3v, wd.x, acc[j].x); acc[j].y = fmaf(s3v, wd.y, acc[j].y);
        acc[j].z = fmaf(s3v, wd.z, acc[j].z); acc[j].w = fmaf(s3v, wd.w, acc[j].w);
      }
    }
  }
  size_t obase = ((size_t)(img0 + li) * 64 + oh * 32) * 81 + p;
  #pragma unroll
  for (int j = 0; j < 8; j++) {
    out[obase + (j * 4 + 0) * 81] = acc[j].x + bias[oh * 32 + j * 4 + 0];
    out[obase + (j * 4 + 1) * 81] = acc[j].y + bias[oh * 32 + j * 4 + 1];
    out[obase + (j * 4 + 2) * 81] = acc[j].z + bias[oh * 32 + j * 4 + 2];
    out[obase + (j * 4 + 3) * 81] = acc[j].w + bias[oh * 32 + j * 4 + 3];
  }
}

// ---------------- conv3: [1024,64,9,9](u8) -> [1024,64,7,7], k3 s1 ----------------
// block = 2 images, 256 thr: waves 0-1 -> oc 0..31, waves 2-3 -> oc 32..63
__global__ __launch_bounds__(256) void k_conv3(const unsigned char* __restrict__ s2,
                                               const float* __restrict__ wT,
                                               const float* __restrict__ bias,
                                               float* __restrict__ out) {
  __shared__ unsigned char sp[10368];
  int tid = threadIdx.x;
  int img0 = blockIdx.x * 2;
  {
    const uint32_t* src = (const uint32_t*)(s2 + (size_t)img0 * 5184);
    uint32_t* dst = (uint32_t*)sp;
    for (int i = tid; i < 2592; i += 256) dst[i] = src[i];
  }
  __syncthreads();
  int oh = __builtin_amdgcn_readfirstlane(tid / 128);   // wave-uniform oc-half
  int t2 = tid % 128;
  if (t2 >= 98) return;
  int li = t2 / 49;
  int p  = t2 % 49;
  int oy = p / 7, ox = p - oy * 7;
  int sbase = li * 5184 + oy * 9 + ox;
  float4 acc[8] = {};
  const float* wb = wT + oh * 32;
  for (int ci = 0; ci < 64; ci++) {
    int soff = sbase + ci * 81;
    const float* w0 = wb + ci * 576;                    // (ci*9)*64
    #pragma unroll
    for (int ky = 0; ky < 3; ky++) {
      float s0 = (float)sp[soff + ky * 9 + 0];
      float s1v = (float)sp[soff + ky * 9 + 1];
      float s2v = (float)sp[soff + ky * 9 + 2];
      const float* wr = w0 + ky * 192;                  // (ky*3)*64
      #pragma unroll
      for (int j = 0; j < 8; j++) {
        float4 wa = ((const float4*)(wr      ))[j];
        float4 wbv = ((const float4*)(wr +  64))[j];
        float4 wc = ((const float4*)(wr + 128))[j];
        acc[j].x = fmaf(s0, wa.x, acc[j].x);  acc[j].y = fmaf(s0, wa.y, acc[j].y);
        acc[j].z = fmaf(s0, wa.z, acc[j].z);  acc[j].w = fmaf(s0, wa.w, acc[j].w);
        acc[j].x = fmaf(s1v, wbv.x, acc[j].x); acc[j].y = fmaf(s1v, wbv.y, acc[j].y);
        acc[j].z = fmaf(s1v, wbv.z, acc[j].z); acc[j].w = fmaf(s1v, wbv.w, acc[j].w);
        acc[j].x = fmaf(s2v, wc.x, acc[j].x); acc[j].y = fmaf(s2v, wc.y, acc[j].y);
        acc[j].z = fmaf(s2v, wc.z, acc[j].z); acc[j].w = fmaf(s2v, wc.w, acc[j].w);
      }
    }
  }
  size_t obase = ((size_t)(img0 + li) * 64 + oh * 32) * 49 + p;
  #pragma unroll
  for (int j = 0; j < 8; j++) {
    out[obase + (j * 4 + 0) * 49] = acc[j].x + bias[oh * 32 + j * 4 + 0];
    out[obase + (j * 4 + 1) * 49] = acc[j].y + bias[oh * 32 + j * 4 + 1];
    out[obase + (j * 4 + 2) * 49] = acc[j].z + bias[oh * 32 + j * 4 + 2];
    out[obase + (j * 4 + 3) * 49] = acc[j].w + bias[oh * 32 + j * 4 + 3];
  }
}

// ---------------- fc1: [1024,3136](u8) x wT[3136,512] -> part[2,1024,512] ----------------
// block: (rowblk of 8 rows, K-half of 1568); thread = 2 oc
__global__ __launch_bounds__(256) void k_fc1(const unsigned char* __restrict__ s3,
                                             const float* __restrict__ wT,
                                             float* __restrict__ part) {
  __shared__ float xs[8 * 392];
  int tid = threadIdx.x;
  int row0  = (blockIdx.x >> 1) * 8;
  int kbase = (blockIdx.x & 1) * 1568;
  int oc2 = tid * 2;
  float2 acc[8];
  #pragma unroll
  for (int r = 0; r < 8; r++) { acc[r].x = 0.f; acc[r].y = 0.f; }
  for (int ch = 0; ch < 4; ch++) {
    int kb = kbase + ch * 392;
    if (ch) __syncthreads();
    for (int i = tid; i < 784; i += 256) {              // 8 rows x 98 u32-words
      int r = i / 98, c = i - r * 98;
      uint32_t wv = *(const uint32_t*)(s3 + (size_t)(row0 + r) * 3136 + kb + c * 4);
      xs[r * 392 + c * 4 + 0] = (float)(wv & 0xffu);
      xs[r * 392 + c * 4 + 1] = (float)((wv >> 8) & 0xffu);
      xs[r * 392 + c * 4 + 2] = (float)((wv >> 16) & 0xffu);
      xs[r * 392 + c * 4 + 3] = (float)((wv >> 24) & 0xffu);
    }
    __syncthreads();
    const float* wp = wT + (size_t)kb * 512 + oc2;
    #pragma unroll 4
    for (int k = 0; k < 392; k++) {
      float2 wv = *(const float2*)(wp + (size_t)k * 512);
      #pragma unroll
      for (int r = 0; r < 8; r++) {
        float sv = xs[r * 392 + k];
        acc[r].x = fmaf(sv, wv.x, acc[r].x);
        acc[r].y = fmaf(sv, wv.y, acc[r].y);
      }
    }
  }
  int khalf = blockIdx.x & 1;
  #pragma unroll
  for (int r = 0; r < 8; r++) {
    float* o = part + (size_t)khalf * 524288 + (size_t)(row0 + r) * 512 + oc2;
    o[0] = acc[r].x; o[1] = acc[r].y;
  }
}

__global__ void k_fc1red(const float* __restrict__ part, const float* __restrict__ bias,
                         float* __restrict__ f1) {
  int idx = blockIdx.x * 256 + threadIdx.x;
  if (idx >= 524288) return;
  f1[idx] = part[idx] + part[524288 + idx] + bias[idx & 511];
}

// ---------------- LIF over fc1 output: [8,128,512] -> spikes u8 ----------------
__global__ void k_lif_fc(const float* __restrict__ f1, unsigned char* __restrict__ hid) {
  int idx = blockIdx.x * 256 + threadIdx.x;
  float v = 0.f;
  #pragma unroll
  for (int t = 0; t < TT; t++) {
    float xv = f1[t * 65536 + idx];
    v = v + (xv - v) * 0.5f;
    unsigned char s = (v >= 1.0f);
    hid[t * 65536 + idx] = s;
    if (s) v = 0.f;
  }
}

// ---------------- fco + mean over T: [8,128,512](u8) -> [128,2] ----------------
__global__ void k_fco(const unsigned char* __restrict__ hid, const float* __restrict__ w,
                      const float* __restrict__ bias, float* __restrict__ out) {
  int b = blockIdx.x, tid = threadIdx.x;
  float a0 = 0.f, a1 = 0.f;
  for (int t = 0; t < TT; t++) {
    const unsigned char* hrow = hid + ((size_t)t * 128 + b) * 512;
    for (int o = tid; o < 512; o += 256) {
      if (hrow[o]) { a0 += w[o]; a1 += w[512 + o]; }
    }
  }
  __shared__ float l0[256], l1[256];
  l0[tid] = a0; l1[tid] = a1; __syncthreads();
  for (int k = 128; k > 0; k >>= 1) {
    if (tid < k) { l0[tid] += l0[tid + k]; l1[tid] += l1[tid + k]; }
    __syncthreads();
  }
  if (tid == 0) {
    out[b * 2 + 0] = l0[0] * 0.125f + bias[0];
    out[b * 2 + 1] = l1[0] * 0.125f + bias[1];
  }
}

extern "C" void kernel_launch(void* const* d_in, const int* in_sizes, int n_in,
                              void* d_out, int out_size, void* d_ws, size_t ws_size,
                              hipStream_t stream) {
  const float* x    = (const float*)d_in[0];
  const float* c1w  = (const float*)d_in[1];
  const float* c1b  = (const float*)d_in[2];
  const float* bn1g = (const float*)d_in[3];
  const float* bn1b = (const float*)d_in[4];
  const float* c2w  = (const float*)d_in[5];
  const float* c2b  = (const float*)d_in[6];
  const float* bn2g = (const float*)d_in[7];
  const float* bn2b = (const float*)d_in[8];
  const float* c3w  = (const float*)d_in[9];
  const float* c3b  = (const float*)d_in[10];
  const float* bn3g = (const float*)d_in[11];
  const float* bn3b = (const float*)d_in[12];
  const float* fc1w = (const float*)d_in[13];
  const float* fc1b = (const float*)d_in[14];
  const float* fcow = (const float*)d_in[15];
  const float* fcob = (const float*)d_in[16];
  float* out = (float*)d_out;

  char* ws = (char*)d_ws;
  // workspace layout (total 64,881,920 B — same proven footprint, with overlays)
  float*         h1   = (float*)(ws + 0);                 //  6,553,600 (dead after lif1)
  unsigned char* s1   = (unsigned char*)(ws + 6553600);   // 13,107,200 (dead after conv2)
  float*         h2   = (float*)(ws + 19660800);          // 21,233,664 (dead after lif2)
  unsigned char* s2   = (unsigned char*)(ws + 40894464);  //  5,308,416
  float*         h3   = (float*)(ws + 46202880);          // 12,845,056
  unsigned char* s3   = (unsigned char*)(ws + 59047936);  //  3,211,264
  float*         f1   = (float*)(ws + 62259200);          //  2,097,152 (written late)
  unsigned char* hid  = (unsigned char*)(ws + 64356352);  //    524,288
  float*         st   = (float*)(ws + 64880640);          //      1,280
  // overlays (scheduled so lifetimes don't overlap):
  float* wT2    = (float*)(ws + 62259200);  // 131,072  in f1 region (dead before fc1red)
  float* wTf    = (float*)(ws + 0);         // 6,422,528 in h1 region (prep after lif1)
  float* wT3    = (float*)(ws + 6553600);   // 147,456  in s1 region (prep after conv2)
  float* f1part = (float*)(ws + 19660800);  // 4,194,304 in h2 region (written in fc1)

  prep_wT2 <<<128, 256, 0, stream>>>(c2w, wT2);
  k_conv1  <<<6400, 256, 0, stream>>>(x, c1w, c1b, h1);
  k_bnstats<400><<<32, 256, 0, stream>>>(h1, 128, 32, st, st + 32);
  k_lif1   <<<6400, 256, 0, stream>>>(h1, st, st + 32, bn1g, bn1b, s1);
  prep_wTf <<<6272, 256, 0, stream>>>(fc1w, wTf);          // h1 region now free

  k_conv2  <<<512, 384, 0, stream>>>(s1, wT2, c2b, h2);
  prep_wT3 <<<144, 256, 0, stream>>>(c3w, wT3);            // s1 region now free
  k_bnstats<81><<<64, 256, 0, stream>>>(h2, 1024, 64, st + 64, st + 128);
  k_lif_seq<<<2592, 256, 0, stream>>>(h2, st + 64, st + 128, bn2g, bn2b, s2, 64, 81, E2_ELEMS);

  k_conv3  <<<512, 256, 0, stream>>>(s2, wT3, c3b, h3);
  k_bnstats<49><<<64, 256, 0, stream>>>(h3, 1024, 64, st + 192, st + 256);
  k_lif_seq<<<1568, 256, 0, stream>>>(h3, st + 192, st + 256, bn3g, bn3b, s3, 64, 49, E3_ELEMS);

  k_fc1    <<<256, 256, 0, stream>>>(s3, wTf, f1part);     // h2 region now free
  k_fc1red <<<2048, 256, 0, stream>>>(f1part, fc1b, f1);   // wT2 region now free
  k_lif_fc <<<256, 256, 0, stream>>>(f1, hid);
  k_fco    <<<128, 256, 0, stream>>>(hid, fcow, fcob, out);
}

// Round 3
// 425.060 us; speedup vs baseline: 8.0730x; 1.9259x over previous
//
#include <hip/hip_runtime.h>
#include <cstdint>
#include <cstddef>

#define TT 8

#define H1_ELEMS (128*32*20*20)   // 1,638,400
#define N2_ELEMS (1024*64*81)     // 5,308,416
#define N3_ELEMS (1024*64*49)     // 3,211,264
#define E2_ELEMS (128*64*81)      // 663,552
#define E3_ELEMS (128*64*49)      // 401,408

// ---------------- weight transpose preps ----------------
__global__ void prep_wT2(const float* __restrict__ w, float* __restrict__ wT) {
  int i = blockIdx.x * 256 + threadIdx.x;           // 64 oc x 512 pos
  if (i >= 64 * 512) return;
  int oc = i & 63, pos = i >> 6;
  wT[pos * 64 + oc] = w[oc * 512 + pos];
}
__global__ void prep_wT3(const float* __restrict__ w, float* __restrict__ wT) {
  int i = blockIdx.x * 256 + threadIdx.x;           // 64 oc x 576 pos
  if (i >= 64 * 576) return;
  int oc = i & 63, pos = i >> 6;
  wT[pos * 64 + oc] = w[oc * 576 + pos];
}
// tiled transpose: w[512][3136] -> wT[3136][512], coalesced both sides
__global__ void prep_wTf(const float* __restrict__ w, float* __restrict__ wT) {
  __shared__ float tile[32][33];
  int k0 = blockIdx.x * 32;                         // 98 tiles
  int o0 = blockIdx.y * 32;                         // 16 tiles
  int tx = threadIdx.x & 31, ty = threadIdx.x >> 5; // 32 x 8
  #pragma unroll
  for (int j = 0; j < 4; j++)
    tile[ty + j * 8][tx] = w[(size_t)(o0 + ty + j * 8) * 3136 + k0 + tx];
  __syncthreads();
  #pragma unroll
  for (int j = 0; j < 4; j++)
    wT[(size_t)(k0 + ty + j * 8) * 512 + o0 + tx] = tile[tx][ty + j * 8];
}

// ---------------- conv1: [128,4,84,84] -> [128,32,20,20], k8 s4 ----------------
__global__ void k_conv1(const float* __restrict__ x, const float* __restrict__ w,
                        const float* __restrict__ bias, float* __restrict__ out) {
  int idx = blockIdx.x * 256 + threadIdx.x;
  if (idx >= H1_ELEMS) return;
  int p  = idx % 400;
  int oc = (idx / 400) & 31;
  int b  = idx / (400 * 32);
  int oy = p / 20, ox = p - oy * 20;
  const float* xb = x + (size_t)b * 28224 + oy * 336 + ox * 4;
  const float* wk = w + oc * 256;
  float acc = 0.f;
  for (int ci = 0; ci < 4; ci++) {
    const float* xc = xb + ci * 7056;
    const float* wc = wk + ci * 64;
    #pragma unroll
    for (int ky = 0; ky < 8; ky++) {
      float4 xa = ((const float4*)(xc + ky * 84))[0];
      float4 xd = ((const float4*)(xc + ky * 84))[1];
      float4 wa = ((const float4*)(wc + ky * 8))[0];
      float4 wd = ((const float4*)(wc + ky * 8))[1];
      acc = fmaf(xa.x, wa.x, acc); acc = fmaf(xa.y, wa.y, acc);
      acc = fmaf(xa.z, wa.z, acc); acc = fmaf(xa.w, wa.w, acc);
      acc = fmaf(xd.x, wd.x, acc); acc = fmaf(xd.y, wd.y, acc);
      acc = fmaf(xd.z, wd.z, acc); acc = fmaf(xd.w, wd.w, acc);
    }
  }
  out[idx] = acc + bias[oc];
}

// ---------------- BN stats, two-stage ----------------
template <int HW>
__global__ void k_bnpartial(const float* __restrict__ xp, int C, int Nper,
                            float* __restrict__ pout) {
  int c = blockIdx.x, s = blockIdx.y, S = gridDim.y, tid = threadIdx.x;
  int n = Nper * HW;
  float sum = 0.f, sum2 = 0.f;
  for (int i = tid; i < n; i += 256) {
    int nb = s * Nper + i / HW;
    int p  = i % HW;
    float v = xp[((size_t)nb * C + c) * HW + p];
    sum += v; sum2 += v * v;
  }
  __shared__ float l0[256], l1[256];
  l0[tid] = sum; l1[tid] = sum2; __syncthreads();
  for (int k = 128; k > 0; k >>= 1) {
    if (tid < k) { l0[tid] += l0[tid + k]; l1[tid] += l1[tid + k]; }
    __syncthreads();
  }
  if (tid == 0) { pout[(c * S + s) * 2] = l0[0]; pout[(c * S + s) * 2 + 1] = l1[0]; }
}

__global__ void k_bnfinal(const float* __restrict__ pin, int S, float n,
                          float* __restrict__ meanArr, float* __restrict__ rstdArr) {
  int c = blockIdx.x, lane = threadIdx.x;
  float s = 0.f, s2 = 0.f;
  if (lane < S) { s = pin[(c * S + lane) * 2]; s2 = pin[(c * S + lane) * 2 + 1]; }
  for (int off = 8; off > 0; off >>= 1) { s += __shfl_down(s, off); s2 += __shfl_down(s2, off); }
  if (lane == 0) {
    float m = s / n;
    float var = s2 / n - m * m;
    meanArr[c] = m;
    rstdArr[c] = rsqrtf(var + 1e-5f);
  }
}

// ---------------- BN + LIF for stage 1 (input identical across T) ----------------
__global__ void k_lif1(const float* __restrict__ h, const float* __restrict__ mean,
                       const float* __restrict__ rstd, const float* __restrict__ g,
                       const float* __restrict__ bb, unsigned char* __restrict__ sout) {
  int idx = blockIdx.x * 256 + threadIdx.x;
  if (idx >= H1_ELEMS) return;
  int c = (idx / 400) & 31;
  float xv = g[c] * (h[idx] - mean[c]) * rstd[c] + bb[c];
  float v = 0.f;
  #pragma unroll
  for (int t = 0; t < TT; t++) {
    v = v + (xv - v) * 0.5f;
    unsigned char s = (v >= 1.0f);
    sout[(size_t)t * H1_ELEMS + idx] = s;
    if (s) v = 0.f;
  }
}

// ---------------- BN + LIF generic (x differs per t) ----------------
__global__ void k_lif_seq(const float* __restrict__ h, const float* __restrict__ mean,
                          const float* __restrict__ rstd, const float* __restrict__ g,
                          const float* __restrict__ bb, unsigned char* __restrict__ sout,
                          int C, int HW, int E) {
  int idx = blockIdx.x * 256 + threadIdx.x;
  if (idx >= E) return;
  int c = (idx / HW) % C;
  float gm = g[c], mm = mean[c], rs = rstd[c], bc = bb[c];
  float v = 0.f;
  #pragma unroll
  for (int t = 0; t < TT; t++) {
    float xv = h[(size_t)t * E + idx];
    xv = gm * (xv - mm) * rs + bc;
    v = v + (xv - v) * 0.5f;
    unsigned char s = (v >= 1.0f);
    sout[(size_t)t * E + idx] = s;
    if (s) v = 0.f;
  }
}

// ---------------- conv2: [1024,32,20,20](u8) -> [1024,64,9,9], k4 s2 ----------------
// block = 2 images, 768 thr (12 waves): 3 waves per oc-quarter (16 oc/thread)
__global__ __launch_bounds__(768) void k_conv2(const unsigned char* __restrict__ s1,
                                               const float* __restrict__ wT,
                                               const float* __restrict__ bias,
                                               float* __restrict__ out) {
  __shared__ unsigned char sp[25600];
  int tid = threadIdx.x;
  int img0 = blockIdx.x * 2;
  {
    const uint32_t* src = (const uint32_t*)(s1 + (size_t)img0 * 12800);
    uint32_t* dst = (uint32_t*)sp;
    for (int i = tid; i < 6400; i += 768) dst[i] = src[i];
  }
  __syncthreads();
  int q  = __builtin_amdgcn_readfirstlane(tid / 192);  // wave-uniform oc-quarter
  int t2 = tid % 192;
  if (t2 >= 162) return;
  int li = t2 / 81;
  int p  = t2 % 81;
  int oy = p / 9, ox = p - oy * 9;
  int sbase = li * 12800 + oy * 40 + ox * 2;
  float4 acc[4] = {};
  const float* wq = wT + q * 16;
  for (int ci = 0; ci < 32; ci++) {
    int soff = sbase + ci * 400;
    const float* w0 = wq + ci * 1024;                   // (ci*16)*64
    #pragma unroll
    for (int ky = 0; ky < 4; ky++) {
      float sv[4];
      sv[0] = (float)sp[soff + ky * 20 + 0];
      sv[1] = (float)sp[soff + ky * 20 + 1];
      sv[2] = (float)sp[soff + ky * 20 + 2];
      sv[3] = (float)sp[soff + ky * 20 + 3];
      const float* wr = w0 + ky * 256;                  // (ky*4)*64
      #pragma unroll
      for (int kx = 0; kx < 4; kx++) {
        const float* wp = wr + kx * 64;
        #pragma unroll
        for (int j = 0; j < 4; j++) {
          float4 wv = ((const float4*)wp)[j];
          acc[j].x = fmaf(sv[kx], wv.x, acc[j].x);
          acc[j].y = fmaf(sv[kx], wv.y, acc[j].y);
          acc[j].z = fmaf(sv[kx], wv.z, acc[j].z);
          acc[j].w = fmaf(sv[kx], wv.w, acc[j].w);
        }
      }
    }
  }
  size_t obase = ((size_t)(img0 + li) * 64 + q * 16) * 81 + p;
  #pragma unroll
  for (int j = 0; j < 4; j++) {
    out[obase + (j * 4 + 0) * 81] = acc[j].x + bias[q * 16 + j * 4 + 0];
    out[obase + (j * 4 + 1) * 81] = acc[j].y + bias[q * 16 + j * 4 + 1];
    out[obase + (j * 4 + 2) * 81] = acc[j].z + bias[q * 16 + j * 4 + 2];
    out[obase + (j * 4 + 3) * 81] = acc[j].w + bias[q * 16 + j * 4 + 3];
  }
}

// ---------------- conv3: [1024,64,9,9](u8) -> [1024,64,7,7], k3 s1 ----------------
// block = 1 image, 256 thr (4 waves): 1 wave per oc-quarter (16 oc/thread)
__global__ __launch_bounds__(256) void k_conv3(const unsigned char* __restrict__ s2,
                                               const float* __restrict__ wT,
                                               const float* __restrict__ bias,
                                               float* __restrict__ out) {
  __shared__ unsigned char sp[5184];
  int tid = threadIdx.x;
  int img = blockIdx.x;
  {
    const uint32_t* src = (const uint32_t*)(s2 + (size_t)img * 5184);
    uint32_t* dst = (uint32_t*)sp;
    for (int i = tid; i < 1296; i += 256) dst[i] = src[i];
  }
  __syncthreads();
  int q = __builtin_amdgcn_readfirstlane(tid >> 6);     // wave-uniform oc-quarter
  int p = tid & 63;
  if (p >= 49) return;
  int oy = p / 7, ox = p - oy * 7;
  int sbase = oy * 9 + ox;
  float4 acc[4] = {};
  const float* wq = wT + q * 16;
  for (int ci = 0; ci < 64; ci++) {
    int soff = sbase + ci * 81;
    const float* w0 = wq + ci * 576;                    // (ci*9)*64
    #pragma unroll
    for (int ky = 0; ky < 3; ky++) {
      float sv[3];
      sv[0] = (float)sp[soff + ky * 9 + 0];
      sv[1] = (float)sp[soff + ky * 9 + 1];
      sv[2] = (float)sp[soff + ky * 9 + 2];
      const float* wr = w0 + ky * 192;                  // (ky*3)*64
      #pragma unroll
      for (int kx = 0; kx < 3; kx++) {
        const float* wp = wr + kx * 64;
        #pragma unroll
        for (int j = 0; j < 4; j++) {
          float4 wv = ((const float4*)wp)[j];
          acc[j].x = fmaf(sv[kx], wv.x, acc[j].x);
          acc[j].y = fmaf(sv[kx], wv.y, acc[j].y);
          acc[j].z = fmaf(sv[kx], wv.z, acc[j].z);
          acc[j].w = fmaf(sv[kx], wv.w, acc[j].w);
        }
      }
    }
  }
  size_t obase = ((size_t)img * 64 + q * 16) * 49 + p;
  #pragma unroll
  for (int j = 0; j < 4; j++) {
    out[obase + (j * 4 + 0) * 49] = acc[j].x + bias[q * 16 + j * 4 + 0];
    out[obase + (j * 4 + 1) * 49] = acc[j].y + bias[q * 16 + j * 4 + 1];
    out[obase + (j * 4 + 2) * 49] = acc[j].z + bias[q * 16 + j * 4 + 2];
    out[obase + (j * 4 + 3) * 49] = acc[j].w + bias[q * 16 + j * 4 + 3];
  }
}

// ---------------- fc1: [1024,3136](u8) x wT[3136,512] -> part[16,1024,512] ----------------
// block: (rowblk of 16 rows) x (K-chunk of 196); thread = 2 oc, 16 rows
__global__ __launch_bounds__(256) void k_fc1(const unsigned char* __restrict__ s3,
                                             const float* __restrict__ wT,
                                             float* __restrict__ part) {
  __shared__ float xs[16 * 196];
  int tid = threadIdx.x;
  int rowblk = blockIdx.x >> 4;
  int kc     = blockIdx.x & 15;
  int row0 = rowblk * 16;
  int kb   = kc * 196;
  for (int i = tid; i < 784; i += 256) {                // 16 rows x 49 u32-words
    int r = i / 49, c = i - r * 49;
    uint32_t wv = *(const uint32_t*)(s3 + (size_t)(row0 + r) * 3136 + kb + c * 4);
    xs[r * 196 + c * 4 + 0] = (float)(wv & 0xffu);
    xs[r * 196 + c * 4 + 1] = (float)((wv >> 8) & 0xffu);
    xs[r * 196 + c * 4 + 2] = (float)((wv >> 16) & 0xffu);
    xs[r * 196 + c * 4 + 3] = (float)((wv >> 24) & 0xffu);
  }
  __syncthreads();
  int oc2 = tid * 2;
  float2 acc[16];
  #pragma unroll
  for (int r = 0; r < 16; r++) { acc[r].x = 0.f; acc[r].y = 0.f; }
  const float* wp = wT + (size_t)kb * 512 + oc2;
  const float4* xs4 = (const float4*)xs;                // [16][49] float4
  for (int k4 = 0; k4 < 49; k4++) {
    float2 w0 = *(const float2*)(wp + (size_t)(k4 * 4 + 0) * 512);
    float2 w1 = *(const float2*)(wp + (size_t)(k4 * 4 + 1) * 512);
    float2 w2 = *(const float2*)(wp + (size_t)(k4 * 4 + 2) * 512);
    float2 w3 = *(const float2*)(wp + (size_t)(k4 * 4 + 3) * 512);
    #pragma unroll
    for (int r = 0; r < 16; r++) {
      float4 xv = xs4[r * 49 + k4];
      acc[r].x = fmaf(xv.x, w0.x, acc[r].x);  acc[r].y = fmaf(xv.x, w0.y, acc[r].y);
      acc[r].x = fmaf(xv.y, w1.x, acc[r].x);  acc[r].y = fmaf(xv.y, w1.y, acc[r].y);
      acc[r].x = fmaf(xv.z, w2.x, acc[r].x);  acc[r].y = fmaf(xv.z, w2.y, acc[r].y);
      acc[r].x = fmaf(xv.w, w3.x, acc[r].x);  acc[r].y = fmaf(xv.w, w3.y, acc[r].y);
    }
  }
  #pragma unroll
  for (int r = 0; r < 16; r++) {
    float* o = part + (size_t)kc * 524288 + (size_t)(row0 + r) * 512 + oc2;
    o[0] = acc[r].x; o[1] = acc[r].y;
  }
}

__global__ void k_fc1red(const float* __restrict__ part, const float* __restrict__ bias,
                         float* __restrict__ f1) {
  int idx = blockIdx.x * 256 + threadIdx.x;
  if (idx >= 524288) return;
  float a = part[idx];
  #pragma unroll
  for (int j = 1; j < 16; j++) a += part[(size_t)j * 524288 + idx];
  f1[idx] = a + bias[idx & 511];
}

// ---------------- LIF over fc1 output: [8,128,512] -> spikes u8 ----------------
__global__ void k_lif_fc(const float* __restrict__ f1, unsigned char* __restrict__ hid) {
  int idx = blockIdx.x * 256 + threadIdx.x;
  float v = 0.f;
  #pragma unroll
  for (int t = 0; t < TT; t++) {
    float xv = f1[t * 65536 + idx];
    v = v + (xv - v) * 0.5f;
    unsigned char s = (v >= 1.0f);
    hid[t * 65536 + idx] = s;
    if (s) v = 0.f;
  }
}

// ---------------- fco + mean over T: [8,128,512](u8) -> [128,2] ----------------
__global__ void k_fco(const unsigned char* __restrict__ hid, const float* __restrict__ w,
                      const float* __restrict__ bias, float* __restrict__ out) {
  int b = blockIdx.x, tid = threadIdx.x;
  float a0 = 0.f, a1 = 0.f;
  for (int t = 0; t < TT; t++) {
    const unsigned char* hrow = hid + ((size_t)t * 128 + b) * 512;
    for (int o = tid; o < 512; o += 256) {
      if (hrow[o]) { a0 += w[o]; a1 += w[512 + o]; }
    }
  }
  __shared__ float l0[256], l1[256];
  l0[tid] = a0; l1[tid] = a1; __syncthreads();
  for (int k = 128; k > 0; k >>= 1) {
    if (tid < k) { l0[tid] += l0[tid + k]; l1[tid] += l1[tid + k]; }
    __syncthreads();
  }
  if (tid == 0) {
    out[b * 2 + 0] = l0[0] * 0.125f + bias[0];
    out[b * 2 + 1] = l1[0] * 0.125f + bias[1];
  }
}

extern "C" void kernel_launch(void* const* d_in, const int* in_sizes, int n_in,
                              void* d_out, int out_size, void* d_ws, size_t ws_size,
                              hipStream_t stream) {
  const float* x    = (const float*)d_in[0];
  const float* c1w  = (const float*)d_in[1];
  const float* c1b  = (const float*)d_in[2];
  const float* bn1g = (const float*)d_in[3];
  const float* bn1b = (const float*)d_in[4];
  const float* c2w  = (const float*)d_in[5];
  const float* c2b  = (const float*)d_in[6];
  const float* bn2g = (const float*)d_in[7];
  const float* bn2b = (const float*)d_in[8];
  const float* c3w  = (const float*)d_in[9];
  const float* c3b  = (const float*)d_in[10];
  const float* bn3g = (const float*)d_in[11];
  const float* bn3b = (const float*)d_in[12];
  const float* fc1w = (const float*)d_in[13];
  const float* fc1b = (const float*)d_in[14];
  const float* fcow = (const float*)d_in[15];
  const float* fcob = (const float*)d_in[16];
  float* out = (float*)d_out;

  char* ws = (char*)d_ws;
  // workspace layout (total 64,881,920 B — same proven footprint, with overlays)
  float*         h1   = (float*)(ws + 0);                 //  6,553,600 (dead after lif1)
  unsigned char* s1   = (unsigned char*)(ws + 6553600);   // 13,107,200 (dead after conv2)
  float*         h2   = (float*)(ws + 19660800);          // 21,233,664 (dead after lif2)
  unsigned char* s2   = (unsigned char*)(ws + 40894464);  //  5,308,416 (dead after conv3)
  float*         h3   = (float*)(ws + 46202880);          // 12,845,056 (dead after lif3)
  unsigned char* s3   = (unsigned char*)(ws + 59047936);  //  3,211,264
  float*         f1   = (float*)(ws + 62259200);          //  2,097,152 (written late)
  unsigned char* hid  = (unsigned char*)(ws + 64356352);  //    524,288
  float*         st   = (float*)(ws + 64880640);          //      1,280
  // overlays (scheduled so lifetimes don't overlap):
  float* wT2    = (float*)(ws + 62259200);  // 131,072  in f1 region (dead before fc1red)
  float* wTf    = (float*)(ws + 0);         // 6,422,528 in h1 region (prep after lif1)
  float* wT3    = (float*)(ws + 6553600);   // 147,456  in s1 region (prep after conv2)
  float* bnpart = (float*)(ws + 6701056);   // 8,192    in s1 region (transient per stage)
  float* f1part = (float*)(ws + 19660800);  // 33,554,432 spans dead h2+s2+h3 (fc1 time)

  prep_wT2 <<<128, 256, 0, stream>>>(c2w, wT2);
  k_conv1  <<<6400, 256, 0, stream>>>(x, c1w, c1b, h1);
  k_bnpartial<400><<<dim3(32, 16), 256, 0, stream>>>(h1, 32, 8, bnpart);
  k_bnfinal<<<32, 64, 0, stream>>>(bnpart, 16, 128.f * 400.f, st, st + 32);
  k_lif1   <<<6400, 256, 0, stream>>>(h1, st, st + 32, bn1g, bn1b, s1);
  prep_wTf <<<dim3(98, 16), 256, 0, stream>>>(fc1w, wTf);  // h1 region now free

  k_conv2  <<<512, 768, 0, stream>>>(s1, wT2, c2b, h2);
  prep_wT3 <<<144, 256, 0, stream>>>(c3w, wT3);            // s1 region now free
  k_bnpartial<81><<<dim3(64, 16), 256, 0, stream>>>(h2, 64, 64, bnpart);
  k_bnfinal<<<64, 64, 0, stream>>>(bnpart, 16, 1024.f * 81.f, st + 64, st + 128);
  k_lif_seq<<<2592, 256, 0, stream>>>(h2, st + 64, st + 128, bn2g, bn2b, s2, 64, 81, E2_ELEMS);

  k_conv3  <<<1024, 256, 0, stream>>>(s2, wT3, c3b, h3);
  k_bnpartial<49><<<dim3(64, 16), 256, 0, stream>>>(h3, 64, 64, bnpart);
  k_bnfinal<<<64, 64, 0, stream>>>(bnpart, 16, 1024.f * 49.f, st + 192, st + 256);
  k_lif_seq<<<1568, 256, 0, stream>>>(h3, st + 192, st + 256, bn3g, bn3b, s3, 64, 49, E3_ELEMS);

  k_fc1    <<<1024, 256, 0, stream>>>(s3, wTf, f1part);    // h2/s2/h3 now free
  k_fc1red <<<2048, 256, 0, stream>>>(f1part, fc1b, f1);   // wT2 region now free
  k_lif_fc <<<256, 256, 0, stream>>>(f1, hid);
  k_fco    <<<128, 256, 0, stream>>>(hid, fcow, fcob, out);
}

// Round 5
// 388.425 us; speedup vs baseline: 8.8344x; 1.0943x over previous
//
#include <hip/hip_runtime.h>
#include <cstdint>
#include <cstddef>

#define TT 8

#define H1_ELEMS (128*32*20*20)   // 1,638,400
#define N2_ELEMS (1024*64*81)     // 5,308,416
#define N3_ELEMS (1024*64*49)     // 3,211,264
#define E2_ELEMS (128*64*81)      // 663,552
#define E3_ELEMS (128*64*49)      // 401,408

__device__ __forceinline__ float ub0(uint32_t v) { return (float)(v & 0xffu); }
__device__ __forceinline__ float ub1(uint32_t v) { return (float)((v >> 8) & 0xffu); }
__device__ __forceinline__ float ub2(uint32_t v) { return (float)((v >> 16) & 0xffu); }
__device__ __forceinline__ float ub3(uint32_t v) { return (float)(v >> 24); }

// ---------------- weight transpose preps ----------------
__global__ void prep_wT1(const float* __restrict__ w, float* __restrict__ wT) {
  int i = blockIdx.x * 256 + threadIdx.x;           // 32 oc x 256 pos
  if (i >= 32 * 256) return;
  int oc = i >> 8, pos = i & 255;
  wT[pos * 32 + oc] = w[oc * 256 + pos];
}
__global__ void prep_wT2(const float* __restrict__ w, float* __restrict__ wT) {
  int i = blockIdx.x * 256 + threadIdx.x;           // 64 oc x 512 pos
  if (i >= 64 * 512) return;
  int oc = i & 63, pos = i >> 6;
  wT[pos * 64 + oc] = w[oc * 512 + pos];
}
__global__ void prep_wT3(const float* __restrict__ w, float* __restrict__ wT) {
  int i = blockIdx.x * 256 + threadIdx.x;           // 64 oc x 576 pos
  if (i >= 64 * 576) return;
  int oc = i & 63, pos = i >> 6;
  wT[pos * 64 + oc] = w[oc * 576 + pos];
}
// tiled transpose: w[512][3136] -> wT[3136][512], coalesced both sides
__global__ void prep_wTf(const float* __restrict__ w, float* __restrict__ wT) {
  __shared__ float tile[32][33];
  int k0 = blockIdx.x * 32;                         // 98 tiles
  int o0 = blockIdx.y * 32;                         // 16 tiles
  int tx = threadIdx.x & 31, ty = threadIdx.x >> 5; // 32 x 8
  #pragma unroll
  for (int j = 0; j < 4; j++)
    tile[ty + j * 8][tx] = w[(size_t)(o0 + ty + j * 8) * 3136 + k0 + tx];
  __syncthreads();
  #pragma unroll
  for (int j = 0; j < 4; j++)
    wT[(size_t)(k0 + ty + j * 8) * 512 + o0 + tx] = tile[tx][ty + j * 8];
}

// ---------------- conv1: [128,4,84,84] -> [128,32,20,20], k8 s4 ----------------
// block = (img, oy-half). LDS slab 4ch x 44rows x 84. thread = 1 px, 32 oc acc.
__global__ __launch_bounds__(256) void k_conv1(const float* __restrict__ x,
                                               const float* __restrict__ wT,
                                               const float* __restrict__ bias,
                                               float* __restrict__ out) {
  __shared__ float xt[14784];                       // 59,136 B
  int tid = threadIdx.x;
  int img  = blockIdx.x >> 1;
  int half = blockIdx.x & 1;
  float4* dst = (float4*)xt;
  #pragma unroll
  for (int ci = 0; ci < 4; ci++) {
    const float4* s4 = (const float4*)(x + (size_t)img * 28224 + ci * 7056 + half * 3360);
    for (int i = tid; i < 924; i += 256) dst[ci * 924 + i] = s4[i];
  }
  __syncthreads();
  if (tid >= 200) return;
  int oyl = tid / 20, ox = tid % 20;
  float acc[32];
  #pragma unroll
  for (int j = 0; j < 32; j++) acc[j] = 0.f;
  int xb0 = oyl * 336 + ox * 4;                     // (oyl*4)*84 + ox*4
  #pragma unroll 1
  for (int ci = 0; ci < 4; ci++) {
    #pragma unroll 1
    for (int ky = 0; ky < 8; ky++) {
      const float* xr = xt + ci * 3696 + xb0 + ky * 84;
      float4 xa  = *(const float4*)xr;
      float4 xbv = *(const float4*)(xr + 4);
      const float* wr = wT + (ci * 8 + ky) * 256;   // wave-uniform -> s_load
      float xs[8] = {xa.x, xa.y, xa.z, xa.w, xbv.x, xbv.y, xbv.z, xbv.w};
      #pragma unroll
      for (int kx = 0; kx < 8; kx++) {
        #pragma unroll
        for (int j = 0; j < 32; j++)
          acc[j] = fmaf(xs[kx], wr[kx * 32 + j], acc[j]);
      }
    }
  }
  size_t obase = (size_t)img * 12800 + (half * 10 + oyl) * 20 + ox;
  #pragma unroll
  for (int j = 0; j < 32; j++) out[obase + j * 400] = acc[j] + bias[j];
}

// ---------------- BN stats, two-stage ----------------
template <int HW>
__global__ void k_bnpartial(const float* __restrict__ xp, int C, int Nper,
                            float* __restrict__ pout) {
  int c = blockIdx.x, s = blockIdx.y, S = gridDim.y, tid = threadIdx.x;
  int n = Nper * HW;
  float sum = 0.f, sum2 = 0.f;
  for (int i = tid; i < n; i += 256) {
    int nb = s * Nper + i / HW;
    int p  = i % HW;
    float v = xp[((size_t)nb * C + c) * HW + p];
    sum += v; sum2 += v * v;
  }
  __shared__ float l0[256], l1[256];
  l0[tid] = sum; l1[tid] = sum2; __syncthreads();
  for (int k = 128; k > 0; k >>= 1) {
    if (tid < k) { l0[tid] += l0[tid + k]; l1[tid] += l1[tid + k]; }
    __syncthreads();
  }
  if (tid == 0) { pout[(c * S + s) * 2] = l0[0]; pout[(c * S + s) * 2 + 1] = l1[0]; }
}

__global__ void k_bnfinal(const float* __restrict__ pin, int S, float n,
                          float* __restrict__ meanArr, float* __restrict__ rstdArr) {
  int c = blockIdx.x, lane = threadIdx.x;
  float s = 0.f, s2 = 0.f;
  if (lane < S) { s = pin[(c * S + lane) * 2]; s2 = pin[(c * S + lane) * 2 + 1]; }
  for (int off = 8; off > 0; off >>= 1) { s += __shfl_down(s, off); s2 += __shfl_down(s2, off); }
  if (lane == 0) {
    float m = s / n;
    float var = s2 / n - m * m;
    meanArr[c] = m;
    rstdArr[c] = rsqrtf(var + 1e-5f);
  }
}

// ---------------- BN + LIF for stage 1 (input identical across T) ----------------
__global__ void k_lif1(const float* __restrict__ h, const float* __restrict__ mean,
                       const float* __restrict__ rstd, const float* __restrict__ g,
                       const float* __restrict__ bb, unsigned char* __restrict__ sout) {
  int idx = blockIdx.x * 256 + threadIdx.x;
  if (idx >= H1_ELEMS) return;
  int c = (idx / 400) & 31;
  float xv = g[c] * (h[idx] - mean[c]) * rstd[c] + bb[c];
  float v = 0.f;
  #pragma unroll
  for (int t = 0; t < TT; t++) {
    v = v + (xv - v) * 0.5f;
    unsigned char s = (v >= 1.0f);
    sout[(size_t)t * H1_ELEMS + idx] = s;
    if (s) v = 0.f;
  }
}

// ---------------- BN + LIF generic (x differs per t) ----------------
__global__ void k_lif_seq(const float* __restrict__ h, const float* __restrict__ mean,
                          const float* __restrict__ rstd, const float* __restrict__ g,
                          const float* __restrict__ bb, unsigned char* __restrict__ sout,
                          int C, int HW, int E) {
  int idx = blockIdx.x * 256 + threadIdx.x;
  if (idx >= E) return;
  int c = (idx / HW) % C;
  float gm = g[c], mm = mean[c], rs = rstd[c], bc = bb[c];
  float v = 0.f;
  #pragma unroll
  for (int t = 0; t < TT; t++) {
    float xv = h[(size_t)t * E + idx];
    xv = gm * (xv - mm) * rs + bc;
    v = v + (xv - v) * 0.5f;
    unsigned char s = (v >= 1.0f);
    sout[(size_t)t * E + idx] = s;
    if (s) v = 0.f;
  }
}

// ---------------- conv2: [1024,32,20,20](u8) -> [1024,64,9,9], k4 s2 ----------------
// block = 2 images, 768 thr. LDS: A = raw u32 stream, B = stream shifted 2 bytes.
__global__ __launch_bounds__(768) void k_conv2(const unsigned char* __restrict__ s1,
                                               const float* __restrict__ wT,
                                               const float* __restrict__ bias,
                                               float* __restrict__ out) {
  __shared__ uint32_t sp2[12800];                   // 51,200 B (A[6400] + B[6400])
  int tid = threadIdx.x;
  int img0 = blockIdx.x * 2;
  {
    const uint32_t* src = (const uint32_t*)(s1 + (size_t)img0 * 12800);
    for (int i = tid; i < 6400; i += 768) {
      uint32_t a = src[i], b = src[i + 1];          // src[6400] stays inside ws
      sp2[i] = a;
      sp2[6400 + i] = (a >> 16) | (b << 16);
    }
  }
  __syncthreads();
  int q  = __builtin_amdgcn_readfirstlane(tid / 192);  // wave-uniform oc-quarter
  int t2 = tid % 192;
  if (t2 >= 162) return;
  int li = t2 / 81;
  int p  = t2 % 81;
  int oy = p / 9, ox = p - oy * 9;
  int sbase = li * 12800 + oy * 40 + ox * 2;        // byte offset, ≡0 or 2 (mod 4)
  int odd = ox & 1;
  const uint32_t* spw = sp2 + (odd ? 6400 : 0);
  int wbase = (sbase - 2 * odd) >> 2;               // aligned word index
  float4 acc[4] = {};
  const float* wq = wT + q * 16;
  #pragma unroll 1
  for (int ci = 0; ci < 32; ci++) {
    int wi = wbase + ci * 100;
    const float* w0 = wq + ci * 1024;               // (ci*16)*64
    #pragma unroll
    for (int ky = 0; ky < 4; ky++) {
      uint32_t wvb = spw[wi + ky * 5];
      float sv[4];
      sv[0] = ub0(wvb);
      sv[1] = ub1(wvb);
      sv[2] = ub2(wvb);
      sv[3] = ub3(wvb);
      const float* wr = w0 + ky * 256;              // (ky*4)*64
      #pragma unroll
      for (int kx = 0; kx < 4; kx++) {
        const float* wp = wr + kx * 64;
        #pragma unroll
        for (int j = 0; j < 4; j++) {
          float4 wv = ((const float4*)wp)[j];
          acc[j].x = fmaf(sv[kx], wv.x, acc[j].x);
          acc[j].y = fmaf(sv[kx], wv.y, acc[j].y);
          acc[j].z = fmaf(sv[kx], wv.z, acc[j].z);
          acc[j].w = fmaf(sv[kx], wv.w, acc[j].w);
        }
      }
    }
  }
  size_t obase = ((size_t)(img0 + li) * 64 + q * 16) * 81 + p;
  #pragma unroll
  for (int j = 0; j < 4; j++) {
    out[obase + (j * 4 + 0) * 81] = acc[j].x + bias[q * 16 + j * 4 + 0];
    out[obase + (j * 4 + 1) * 81] = acc[j].y + bias[q * 16 + j * 4 + 1];
    out[obase + (j * 4 + 2) * 81] = acc[j].z + bias[q * 16 + j * 4 + 2];
    out[obase + (j * 4 + 3) * 81] = acc[j].w + bias[q * 16 + j * 4 + 3];
  }
}

// ---------------- conv3: [1024,64,9,9](u8) -> [1024,64,7,7], k3 s1 ----------------
// block = 1 image, 256 thr. LDS: 4 byte-shifted u32 copies (residues 0..3).
__global__ __launch_bounds__(256) void k_conv3(const unsigned char* __restrict__ s2,
                                               const float* __restrict__ wT,
                                               const float* __restrict__ bias,
                                               float* __restrict__ out) {
  __shared__ uint32_t spc[5184];                    // 20,736 B = 4 copies x 1296
  int tid = threadIdx.x;
  int img = blockIdx.x;
  {
    const uint32_t* src = (const uint32_t*)(s2 + (size_t)img * 5184);
    for (int i = tid; i < 1296; i += 256) {
      uint32_t a = src[i], b = src[i + 1];          // src[1296] stays inside ws
      spc[i]        = a;
      spc[1296 + i] = (a >> 8)  | (b << 24);
      spc[2592 + i] = (a >> 16) | (b << 16);
      spc[3888 + i] = (a >> 24) | (b << 8);
    }
  }
  __syncthreads();
  int q = __builtin_amdgcn_readfirstlane(tid >> 6); // wave-uniform oc-quarter
  int p = tid & 63;
  if (p >= 49) return;
  int oy = p / 7, ox = p - oy * 7;
  int sbase = oy * 9 + ox;
  float4 acc[4] = {};
  const float* wq = wT + q * 16;
  #pragma unroll 1
  for (int ci = 0; ci < 64; ci++) {
    int o0 = sbase + ci * 81;
    const float* w0 = wq + ci * 576;                // (ci*9)*64
    #pragma unroll
    for (int ky = 0; ky < 3; ky++) {
      int o = o0 + ky * 9;
      uint32_t wvb = spc[(o & 3) * 1296 + (o >> 2)];
      float sv[3];
      sv[0] = ub0(wvb);
      sv[1] = ub1(wvb);
      sv[2] = ub2(wvb);
      const float* wr = w0 + ky * 192;              // (ky*3)*64
      #pragma unroll
      for (int kx = 0; kx < 3; kx++) {
        const float* wp = wr + kx * 64;
        #pragma unroll
        for (int j = 0; j < 4; j++) {
          float4 wv = ((const float4*)wp)[j];
          acc[j].x = fmaf(sv[kx], wv.x, acc[j].x);
          acc[j].y = fmaf(sv[kx], wv.y, acc[j].y);
          acc[j].z = fmaf(sv[kx], wv.z, acc[j].z);
          acc[j].w = fmaf(sv[kx], wv.w, acc[j].w);
        }
      }
    }
  }
  size_t obase = ((size_t)img * 64 + q * 16) * 49 + p;
  #pragma unroll
  for (int j = 0; j < 4; j++) {
    out[obase + (j * 4 + 0) * 49] = acc[j].x + bias[q * 16 + j * 4 + 0];
    out[obase + (j * 4 + 1) * 49] = acc[j].y + bias[q * 16 + j * 4 + 1];
    out[obase + (j * 4 + 2) * 49] = acc[j].z + bias[q * 16 + j * 4 + 2];
    out[obase + (j * 4 + 3) * 49] = acc[j].w + bias[q * 16 + j * 4 + 3];
  }
}

// ---------------- fc1: [1024,3136](u8) x wT[3136,512] -> part[16,1024,512] ----------------
__global__ __launch_bounds__(256) void k_fc1(const unsigned char* __restrict__ s3,
                                             const float* __restrict__ wT,
                                             float* __restrict__ part) {
  __shared__ float xs[16 * 196];
  int tid = threadIdx.x;
  int rowblk = blockIdx.x >> 4;
  int kc     = blockIdx.x & 15;
  int row0 = rowblk * 16;
  int kb   = kc * 196;
  for (int i = tid; i < 784; i += 256) {            // 16 rows x 49 u32-words
    int r = i / 49, c = i - r * 49;
    uint32_t wv = *(const uint32_t*)(s3 + (size_t)(row0 + r) * 3136 + kb + c * 4);
    xs[r * 196 + c * 4 + 0] = ub0(wv);
    xs[r * 196 + c * 4 + 1] = ub1(wv);
    xs[r * 196 + c * 4 + 2] = ub2(wv);
    xs[r * 196 + c * 4 + 3] = ub3(wv);
  }
  __syncthreads();
  int oc2 = tid * 2;
  float2 acc[16];
  #pragma unroll
  for (int r = 0; r < 16; r++) { acc[r].x = 0.f; acc[r].y = 0.f; }
  const float* wp = wT + (size_t)kb * 512 + oc2;
  const float4* xs4 = (const float4*)xs;            // [16][49] float4
  for (int k4 = 0; k4 < 49; k4++) {
    float2 w0 = *(const float2*)(wp + (size_t)(k4 * 4 + 0) * 512);
    float2 w1 = *(const float2*)(wp + (size_t)(k4 * 4 + 1) * 512);
    float2 w2 = *(const float2*)(wp + (size_t)(k4 * 4 + 2) * 512);
    float2 w3 = *(const float2*)(wp + (size_t)(k4 * 4 + 3) * 512);
    #pragma unroll
    for (int r = 0; r < 16; r++) {
      float4 xv = xs4[r * 49 + k4];
      acc[r].x = fmaf(xv.x, w0.x, acc[r].x);  acc[r].y = fmaf(xv.x, w0.y, acc[r].y);
      acc[r].x = fmaf(xv.y, w1.x, acc[r].x);  acc[r].y = fmaf(xv.y, w1.y, acc[r].y);
      acc[r].x = fmaf(xv.z, w2.x, acc[r].x);  acc[r].y = fmaf(xv.z, w2.y, acc[r].y);
      acc[r].x = fmaf(xv.w, w3.x, acc[r].x);  acc[r].y = fmaf(xv.w, w3.y, acc[r].y);
    }
  }
  #pragma unroll
  for (int r = 0; r < 16; r++) {
    float* o = part + (size_t)kc * 524288 + (size_t)(row0 + r) * 512 + oc2;
    o[0] = acc[r].x; o[1] = acc[r].y;
  }
}

__global__ void k_fc1red(const float* __restrict__ part, const float* __restrict__ bias,
                         float* __restrict__ f1) {
  int idx = blockIdx.x * 256 + threadIdx.x;
  if (idx >= 524288) return;
  float a = part[idx];
  #pragma unroll
  for (int j = 1; j < 16; j++) a += part[(size_t)j * 524288 + idx];
  f1[idx] = a + bias[idx & 511];
}

// ---------------- LIF over fc1 output: [8,128,512] -> spikes u8 ----------------
__global__ void k_lif_fc(const float* __restrict__ f1, unsigned char* __restrict__ hid) {
  int idx = blockIdx.x * 256 + threadIdx.x;
  float v = 0.f;
  #pragma unroll
  for (int t = 0; t < TT; t++) {
    float xv = f1[t * 65536 + idx];
    v = v + (xv - v) * 0.5f;
    unsigned char s = (v >= 1.0f);
    hid[t * 65536 + idx] = s;
    if (s) v = 0.f;
  }
}

// ---------------- fco + mean over T: [8,128,512](u8) -> [128,2] ----------------
__global__ void k_fco(const unsigned char* __restrict__ hid, const float* __restrict__ w,
                      const float* __restrict__ bias, float* __restrict__ out) {
  int b = blockIdx.x, tid = threadIdx.x;
  float a0 = 0.f, a1 = 0.f;
  for (int t = 0; t < TT; t++) {
    const unsigned char* hrow = hid + ((size_t)t * 128 + b) * 512;
    for (int o = tid; o < 512; o += 256) {
      if (hrow[o]) { a0 += w[o]; a1 += w[512 + o]; }
    }
  }
  __shared__ float l0[256], l1[256];
  l0[tid] = a0; l1[tid] = a1; __syncthreads();
  for (int k = 128; k > 0; k >>= 1) {
    if (tid < k) { l0[tid] += l0[tid + k]; l1[tid] += l1[tid + k]; }
    __syncthreads();
  }
  if (tid == 0) {
    out[b * 2 + 0] = l0[0] * 0.125f + bias[0];
    out[b * 2 + 1] = l1[0] * 0.125f + bias[1];
  }
}

extern "C" void kernel_launch(void* const* d_in, const int* in_sizes, int n_in,
                              void* d_out, int out_size, void* d_ws, size_t ws_size,
                              hipStream_t stream) {
  const float* x    = (const float*)d_in[0];
  const float* c1w  = (const float*)d_in[1];
  const float* c1b  = (const float*)d_in[2];
  const float* bn1g = (const float*)d_in[3];
  const float* bn1b = (const float*)d_in[4];
  const float* c2w  = (const float*)d_in[5];
  const float* c2b  = (const float*)d_in[6];
  const float* bn2g = (const float*)d_in[7];
  const float* bn2b = (const float*)d_in[8];
  const float* c3w  = (const float*)d_in[9];
  const float* c3b  = (const float*)d_in[10];
  const float* bn3g = (const float*)d_in[11];
  const float* bn3b = (const float*)d_in[12];
  const float* fc1w = (const float*)d_in[13];
  const float* fc1b = (const float*)d_in[14];
  const float* fcow = (const float*)d_in[15];
  const float* fcob = (const float*)d_in[16];
  float* out = (float*)d_out;

  char* ws = (char*)d_ws;
  // workspace layout (total 64,881,920 B — same proven footprint, with overlays)
  float*         h1   = (float*)(ws + 0);                 //  6,553,600 (dead after lif1)
  unsigned char* s1   = (unsigned char*)(ws + 6553600);   // 13,107,200 (dead after conv2)
  float*         h2   = (float*)(ws + 19660800);          // 21,233,664 (dead after lif2)
  unsigned char* s2   = (unsigned char*)(ws + 40894464);  //  5,308,416 (dead after conv3)
  float*         h3   = (float*)(ws + 46202880);          // 12,845,056 (dead after lif3)
  unsigned char* s3   = (unsigned char*)(ws + 59047936);  //  3,211,264
  float*         f1   = (float*)(ws + 62259200);          //  2,097,152 (written late)
  unsigned char* hid  = (unsigned char*)(ws + 64356352);  //    524,288
  float*         st   = (float*)(ws + 64880640);          //      1,280
  // overlays (scheduled so lifetimes don't overlap):
  float* wT2    = (float*)(ws + 62259200);  // 131,072  in f1 region (dead before fc1red)
  float* wT1    = (float*)(ws + 62390272);  // 32,768   in f1 region (dead before fc1red)
  float* wTf    = (float*)(ws + 0);         // 6,422,528 in h1 region (prep after lif1)
  float* wT3    = (float*)(ws + 6553600);   // 147,456  in s1 region (prep after conv2)
  float* bnpart = (float*)(ws + 6701056);   // 8,192    in s1 region (consumed before lif1 writes s1)
  float* f1part = (float*)(ws + 19660800);  // 33,554,432 spans dead h2+s2+h3 (fc1 time)

  prep_wT1 <<<32, 256, 0, stream>>>(c1w, wT1);
  prep_wT2 <<<128, 256, 0, stream>>>(c2w, wT2);
  k_conv1  <<<256, 256, 0, stream>>>(x, wT1, c1b, h1);
  k_bnpartial<400><<<dim3(32, 16), 256, 0, stream>>>(h1, 32, 8, bnpart);
  k_bnfinal<<<32, 64, 0, stream>>>(bnpart, 16, 128.f * 400.f, st, st + 32);
  k_lif1   <<<6400, 256, 0, stream>>>(h1, st, st + 32, bn1g, bn1b, s1);
  prep_wTf <<<dim3(98, 16), 256, 0, stream>>>(fc1w, wTf);  // h1 region now free

  k_conv2  <<<512, 768, 0, stream>>>(s1, wT2, c2b, h2);
  prep_wT3 <<<144, 256, 0, stream>>>(c3w, wT3);            // s1 region now free
  k_bnpartial<81><<<dim3(64, 16), 256, 0, stream>>>(h2, 64, 64, bnpart);
  k_bnfinal<<<64, 64, 0, stream>>>(bnpart, 16, 1024.f * 81.f, st + 64, st + 128);
  k_lif_seq<<<2592, 256, 0, stream>>>(h2, st + 64, st + 128, bn2g, bn2b, s2, 64, 81, E2_ELEMS);

  k_conv3  <<<1024, 256, 0, stream>>>(s2, wT3, c3b, h3);
  k_bnpartial<49><<<dim3(64, 16), 256, 0, stream>>>(h3, 64, 64, bnpart);
  k_bnfinal<<<64, 64, 0, stream>>>(bnpart, 16, 1024.f * 49.f, st + 192, st + 256);
  k_lif_seq<<<1568, 256, 0, stream>>>(h3, st + 192, st + 256, bn3g, bn3b, s3, 64, 49, E3_ELEMS);

  k_fc1    <<<1024, 256, 0, stream>>>(s3, wTf, f1part);    // h2/s2/h3 now free
  k_fc1red <<<2048, 256, 0, stream>>>(f1part, fc1b, f1);   // wT1/wT2 regions now free
  k_lif_fc <<<256, 256, 0, stream>>>(f1, hid);
  k_fco    <<<128, 256, 0, stream>>>(hid, fcow, fcob, out);
}